// Round 8
// baseline (4674.038 us; speedup 1.0000x reference)
//
#include <hip/hip_runtime.h>

// FFJORD B=4096 D=64 C=16 H=512, NBIJ=2, NSTEPS=8 RK4 -> 64 sequential MLP+VJP evals.
// Round 8: 2 blocks/CU for load concurrency. M=8 rows/block, grid=512, 512 thr,
// __launch_bounds__(512,4) caps total regs at 128 (16 acc -> AGPR, arch <= 112) so
// two 8-wave blocks co-reside (LDS 64.4KB x2 = 129KB <= 160KB). e3 = eps@W3^T hoisted
// per bijector (LDS); g2 written in-place into h2A (extra barrier) to keep LDS small.

typedef __attribute__((ext_vector_type(8))) short short8;
typedef __attribute__((ext_vector_type(4))) float f32x4;

#define MFMA_B16(a, b, c) __builtin_amdgcn_mfma_f32_16x16x32_bf16((a), (b), (c), 0, 0, 0)

__device__ __forceinline__ unsigned short f2bf(float f) {
  union { float f; unsigned u; } v; v.f = f;
  return (unsigned short)((v.u + 0x7FFFu + ((v.u >> 16) & 1u)) >> 16);
}
__device__ __forceinline__ float bf2f(unsigned short u) {
  union { unsigned u; float f; } v; v.u = ((unsigned)u) << 16; return v.f;
}
__device__ __forceinline__ float fast_tanh(float x) {
  float e = __expf(2.f * x);
  return 1.f - 2.f * __builtin_amdgcn_rcpf(e + 1.f);
}

// ws layout (ushort units), all bf16 column-major W[n][k]:
// W1f [2][512][96]  @ 0        (k>=81 zero-padded)
// W2f [2][512][512] @ 98304    (W2^T data: forward B)
// W2b [2][512][512] @ 622592   (plain W2: backward B)
// W3f [2][64][512]  @ 1146880  (W3^T: forward B)
// W3b [2][512][64]  @ 1212416  (plain W3: B for e3 = eps@W3^T, once per bijector)
// W1y [2][64][512]  @ 1277952  (first 64 rows of W1)

__global__ void prep_bf16(const float* __restrict__ W1, const float* __restrict__ W2,
                          const float* __restrict__ W3, unsigned short* __restrict__ ws) {
  int o = blockIdx.x * 256 + threadIdx.x;
  if (o < 98304) {
    int ib = o / 49152, r = o % 49152, n = r / 96, k = r % 96;
    ws[o] = (k < 81) ? f2bf(W1[(size_t)ib * 41472 + k * 512 + n]) : (unsigned short)0;
  } else if (o < 622592) {
    int o2 = o - 98304;
    int ib = o2 / 262144, r = o2 % 262144, n = r / 512, k = r % 512;
    ws[o] = f2bf(W2[(size_t)ib * 262144 + k * 512 + n]);
  } else if (o < 1146880) {
    ws[o] = f2bf(W2[o - 622592]);
  } else if (o < 1212416) {
    int o2 = o - 1146880;
    int ib = o2 / 32768, r = o2 % 32768, n = r / 512, k = r % 512;
    ws[o] = f2bf(W3[(size_t)ib * 32768 + k * 64 + n]);
  } else if (o < 1277952) {
    ws[o] = f2bf(W3[o - 1212416]);
  } else if (o < 1343488) {
    int o2 = o - 1277952;
    int ib = o2 / 32768, r = o2 % 32768, n = r / 512, k = r % 512;
    ws[o] = f2bf(W1[(size_t)ib * 41472 + n * 512 + k]);
  }
}

#define ZS 104   // z A-buffer stride (K=96 used)
#define HS 520   // h buffers stride (K=512)
#define ES 72    // eps stride (K=64)

__global__ __launch_bounds__(512, 4) void ffjord_mfma(
    const float* __restrict__ x, const float* __restrict__ cond, const float* __restrict__ eps,
    const float* __restrict__ b1g, const float* __restrict__ b2g, const float* __restrict__ b3g,
    const unsigned short* __restrict__ ws, float* __restrict__ out) {
  __shared__ unsigned short zA[16 * ZS];
  __shared__ unsigned short h1A[16 * HS];   // h1; overwritten by g1 in GEMM4b
  __shared__ unsigned short h2A[16 * HS];   // h2; overwritten by g2 (in-place) after GEMM3f
  __shared__ unsigned short e3A[16 * HS];   // e3 = eps @ W3^T, constant per bijector
  __shared__ unsigned short epsA[16 * ES];
  __shared__ float eps_s[8][64];
  __shared__ float f_s[8][64];
  __shared__ float ycur[8][64], ytmp[8][64], yacc[8][64];
  __shared__ float l_row[8], ld_row[8], ldacc[8];

  const int t = threadIdx.x;
  const int wave = t >> 6;
  const int lane = t & 63;
  const int lane15 = lane & 15;
  const int q8 = (lane >> 4) * 8;       // frag k-offset; C/D row base = q8>>1
  const int row0 = blockIdx.x * 8;
  const int ws64 = wave * 64;
  const int tm = t >> 6, td = t & 63;   // thread-own element (512 = 8x64)

  // init: rows 0..7 state; zero MFMA A-rows 8..15 of zA/epsA
  {
    float xv = x[(size_t)(row0 + tm) * 64 + td];
    ycur[tm][td] = xv; ytmp[tm][td] = xv;
  }
  for (int e = t; e < 8 * ZS; e += 512) zA[8 * ZS + e] = 0;
  for (int e = t; e < 8 * ES; e += 512) epsA[8 * ES + e] = 0;
  if (t < 256) {
    int m = t >> 5, kk = t & 31;   // rows 0..7, cols 64..95
    zA[m * ZS + 64 + kk] = (kk < 16) ? f2bf(cond[(size_t)(row0 + m) * 16 + kk]) : (unsigned short)0;
  }
  if (t < 8) ld_row[t] = 0.f;

  const float dt = 0.125f;
  const float w06 = dt / 6.f, w13 = dt / 3.f;

  for (int ib = 0; ib < 2; ++ib) {
    const unsigned short* W1f = ws + 0       + ib * 49152;
    const unsigned short* W2f = ws + 98304   + ib * 262144;
    const unsigned short* W2b = ws + 622592  + ib * 262144;
    const unsigned short* W3f = ws + 1146880 + ib * 32768;
    const unsigned short* W3b = ws + 1212416 + ib * 32768;
    const unsigned short* W1y = ws + 1277952 + ib * 32768;
    const float* b1b = b1g + ib * 512;
    const float* b2b = b2g + ib * 512;
    const float* b3b = b3g + ib * 64;

    {
      float ev = eps[((size_t)ib * 4096 + row0 + tm) * 64 + td];
      eps_s[tm][td] = ev;
      epsA[tm * ES + td] = f2bf(ev);
    }
    __syncthreads();

    // ---- e3 = eps @ W3^T (N=512, K=64), ONCE per bijector (rows 8..15 = 0) ----
    {
      f32x4 a0 = {0,0,0,0}, a1 = {0,0,0,0}, a2 = {0,0,0,0}, a3 = {0,0,0,0};
      const unsigned short* ap = epsA + lane15 * ES + q8;
      const unsigned short* wp = W3b + (size_t)(ws64 + lane15) * 64 + q8;
      #pragma unroll
      for (int kk = 0; kk < 64; kk += 32) {
        short8 a = *(const short8*)(ap + kk);
        a0 = MFMA_B16(a, *(const short8*)(wp + kk),           a0);
        a1 = MFMA_B16(a, *(const short8*)(wp + 16 * 64 + kk), a1);
        a2 = MFMA_B16(a, *(const short8*)(wp + 32 * 64 + kk), a2);
        a3 = MFMA_B16(a, *(const short8*)(wp + 48 * 64 + kk), a3);
      }
      f32x4 acc[4] = {a0, a1, a2, a3};
      #pragma unroll
      for (int tl = 0; tl < 4; ++tl) {
        int n = ws64 + tl * 16 + lane15;
        #pragma unroll
        for (int rg = 0; rg < 4; ++rg)
          e3A[((q8 >> 1) + rg) * HS + n] = f2bf(acc[tl][rg]);
      }
    }
    __syncthreads();

    for (int it = 0; it < 32; ++it) {
      const int s = it & 3;
      const float te = (it >> 2) * dt + ((s == 0) ? 0.f : (s == 3) ? dt : 0.5f * dt);

      // ---- z build + zero accumulators ----
      zA[tm * ZS + td] = f2bf(ytmp[tm][td]);
      f_s[tm][td] = 0.f;
      if (t < 8) { zA[t * ZS + 80] = f2bf(te); l_row[t] = 0.f; }
      __syncthreads();

      // ---- GEMM1: h1 = tanh(z @ W1 + b1), K=96, N=512 ----
      {
        f32x4 a0 = {0,0,0,0}, a1 = {0,0,0,0}, a2 = {0,0,0,0}, a3 = {0,0,0,0};
        const unsigned short* ap = zA + lane15 * ZS + q8;
        const unsigned short* wp = W1f + (size_t)(ws64 + lane15) * 96 + q8;
        #pragma unroll
        for (int k0 = 0; k0 < 96; k0 += 32) {
          short8 a = *(const short8*)(ap + k0);
          a0 = MFMA_B16(a, *(const short8*)(wp + k0),           a0);
          a1 = MFMA_B16(a, *(const short8*)(wp + 16 * 96 + k0), a1);
          a2 = MFMA_B16(a, *(const short8*)(wp + 32 * 96 + k0), a2);
          a3 = MFMA_B16(a, *(const short8*)(wp + 48 * 96 + k0), a3);
        }
        f32x4 acc[4] = {a0, a1, a2, a3};
        #pragma unroll
        for (int tl = 0; tl < 4; ++tl) {
          int n = ws64 + tl * 16 + lane15;
          float bias = b1b[n];
          #pragma unroll
          for (int rg = 0; rg < 4; ++rg)
            h1A[((q8 >> 1) + rg) * HS + n] = f2bf(fast_tanh(acc[tl][rg] + bias));
        }
      }
      __syncthreads();

      // ---- GEMM2: h2 = tanh(h1 @ W2 + b2), K=512, N=512 ----
      {
        f32x4 a0 = {0,0,0,0}, a1 = {0,0,0,0}, a2 = {0,0,0,0}, a3 = {0,0,0,0};
        const unsigned short* ap = h1A + lane15 * HS + q8;
        const unsigned short* wp = W2f + (size_t)(ws64 + lane15) * 512 + q8;
        #pragma unroll 4
        for (int k0 = 0; k0 < 512; k0 += 32) {
          short8 a = *(const short8*)(ap + k0);
          a0 = MFMA_B16(a, *(const short8*)(wp + k0),            a0);
          a1 = MFMA_B16(a, *(const short8*)(wp + 16 * 512 + k0), a1);
          a2 = MFMA_B16(a, *(const short8*)(wp + 32 * 512 + k0), a2);
          a3 = MFMA_B16(a, *(const short8*)(wp + 48 * 512 + k0), a3);
        }
        f32x4 acc[4] = {a0, a1, a2, a3};
        #pragma unroll
        for (int tl = 0; tl < 4; ++tl) {
          int n = ws64 + tl * 16 + lane15;
          float bias = b2b[n];
          #pragma unroll
          for (int rg = 0; rg < 4; ++rg)
            h2A[((q8 >> 1) + rg) * HS + n] = f2bf(fast_tanh(acc[tl][rg] + bias));
        }
      }
      __syncthreads();

      // ---- GEMM3f: f += h2 @ W3f (N=64, K split 8 ways x 64) ----
      {
        f32x4 a0 = {0,0,0,0}, a1 = {0,0,0,0}, a2 = {0,0,0,0}, a3 = {0,0,0,0};
        const unsigned short* ap = h2A + lane15 * HS + ws64 + q8;
        const unsigned short* wp = W3f + (size_t)lane15 * 512 + ws64 + q8;
        #pragma unroll
        for (int kk = 0; kk < 64; kk += 32) {
          short8 a = *(const short8*)(ap + kk);
          a0 = MFMA_B16(a, *(const short8*)(wp + kk),            a0);
          a1 = MFMA_B16(a, *(const short8*)(wp + 16 * 512 + kk), a1);
          a2 = MFMA_B16(a, *(const short8*)(wp + 32 * 512 + kk), a2);
          a3 = MFMA_B16(a, *(const short8*)(wp + 48 * 512 + kk), a3);
        }
        f32x4 acc[4] = {a0, a1, a2, a3};
        if (lane < 32) {   // C rows 0..7 only
          #pragma unroll
          for (int tl = 0; tl < 4; ++tl)
            #pragma unroll
            for (int rg = 0; rg < 4; ++rg)
              atomicAdd(&f_s[(q8 >> 1) + rg][tl * 16 + lane15], acc[tl][rg]);
        }
      }
      __syncthreads();

      // ---- g2 = e3 * (1 - h2^2) IN-PLACE into h2A (rows 8..15 become 0) ----
      #pragma unroll
      for (int j = 0; j < 16; ++j) {
        int idx = t + j * 512;
        int m = idx >> 9, n = idx & 511;
        float h = bf2f(h2A[m * HS + n]);
        h2A[m * HS + n] = f2bf(bf2f(e3A[m * HS + n]) * (1.f - h * h));
      }
      __syncthreads();

      // ---- GEMM4b: g1 = (g2 @ W2^T) * (1 - h1^2) -> h1A in place ----
      {
        f32x4 a0 = {0,0,0,0}, a1 = {0,0,0,0}, a2 = {0,0,0,0}, a3 = {0,0,0,0};
        const unsigned short* ap = h2A + lane15 * HS + q8;
        const unsigned short* wp = W2b + (size_t)(ws64 + lane15) * 512 + q8;
        #pragma unroll 4
        for (int k0 = 0; k0 < 512; k0 += 32) {
          short8 a = *(const short8*)(ap + k0);
          a0 = MFMA_B16(a, *(const short8*)(wp + k0),            a0);
          a1 = MFMA_B16(a, *(const short8*)(wp + 16 * 512 + k0), a1);
          a2 = MFMA_B16(a, *(const short8*)(wp + 32 * 512 + k0), a2);
          a3 = MFMA_B16(a, *(const short8*)(wp + 48 * 512 + k0), a3);
        }
        f32x4 acc[4] = {a0, a1, a2, a3};
        #pragma unroll
        for (int tl = 0; tl < 4; ++tl) {
          int n = ws64 + tl * 16 + lane15;
          #pragma unroll
          for (int rg = 0; rg < 4; ++rg) {
            int m = (q8 >> 1) + rg;
            float h = bf2f(h1A[m * HS + n]);
            h1A[m * HS + n] = f2bf(acc[tl][rg] * (1.f - h * h));
          }
        }
      }
      __syncthreads();

      // ---- GEMM5b: gz = g1 @ W1y^T (N=64, K split 8 ways), l = sum(gz*eps) ----
      {
        f32x4 a0 = {0,0,0,0}, a1 = {0,0,0,0}, a2 = {0,0,0,0}, a3 = {0,0,0,0};
        const unsigned short* ap = h1A + lane15 * HS + ws64 + q8;
        const unsigned short* wp = W1y + (size_t)lane15 * 512 + ws64 + q8;
        #pragma unroll
        for (int kk = 0; kk < 64; kk += 32) {
          short8 a = *(const short8*)(ap + kk);
          a0 = MFMA_B16(a, *(const short8*)(wp + kk),            a0);
          a1 = MFMA_B16(a, *(const short8*)(wp + 16 * 512 + kk), a1);
          a2 = MFMA_B16(a, *(const short8*)(wp + 32 * 512 + kk), a2);
          a3 = MFMA_B16(a, *(const short8*)(wp + 48 * 512 + kk), a3);
        }
        f32x4 acc[4] = {a0, a1, a2, a3};
        if (lane < 32) {   // C rows 0..7 only
          #pragma unroll
          for (int rg = 0; rg < 4; ++rg) {
            int m = (q8 >> 1) + rg;
            float p = acc[0][rg] * eps_s[m][lane15]
                    + acc[1][rg] * eps_s[m][16 + lane15]
                    + acc[2][rg] * eps_s[m][32 + lane15]
                    + acc[3][rg] * eps_s[m][48 + lane15];
            #pragma unroll
            for (int o = 1; o < 16; o <<= 1) p += __shfl_xor(p, o);
            if (lane15 == 0) atomicAdd(&l_row[m], p);
          }
        }
      }
      __syncthreads();

      // ---- RK4 update (thread owns (tm,td)) ----
      {
        const float wk = (s == 0 || s == 3) ? w06 : w13;
        float fv = f_s[tm][td] + b3b[td];
        if (s == 0)      yacc[tm][td] = ycur[tm][td] + w06 * fv;
        else if (s < 3)  yacc[tm][td] += wk * fv;
        if (s < 3) {
          ytmp[tm][td] = ycur[tm][td] + ((s == 2) ? dt : 0.5f * dt) * fv;
        } else {
          float yn = yacc[tm][td] + w06 * fv;
          ycur[tm][td] = yn; ytmp[tm][td] = yn;
        }
        if (t < 8) {
          float lv = l_row[t];
          if (s == 0)      ldacc[t] = w06 * lv;
          else if (s < 3)  ldacc[t] += wk * lv;
          else             ld_row[t] += ldacc[t] + w06 * lv;
        }
      }
      __syncthreads();
    }
  }

  out[(size_t)(row0 + tm) * 65 + td] = ycur[tm][td];
  if (t < 8) out[(size_t)(row0 + t) * 65 + 64] = ld_row[t];
}

extern "C" void kernel_launch(void* const* d_in, const int* in_sizes, int n_in,
                              void* d_out, int out_size, void* d_ws, size_t ws_size,
                              hipStream_t stream) {
  (void)in_sizes; (void)n_in; (void)out_size; (void)ws_size;
  const float* x    = (const float*)d_in[0];
  const float* cond = (const float*)d_in[1];
  const float* eps  = (const float*)d_in[2];
  const float* W1   = (const float*)d_in[3];
  const float* b1   = (const float*)d_in[4];
  const float* W2   = (const float*)d_in[5];
  const float* b2   = (const float*)d_in[6];
  const float* W3   = (const float*)d_in[7];
  const float* b3   = (const float*)d_in[8];
  float* out = (float*)d_out;
  unsigned short* ws = (unsigned short*)d_ws;

  const int prep_total = 1343488;
  prep_bf16<<<(prep_total + 255) / 256, 256, 0, stream>>>(W1, W2, W3, ws);
  ffjord_mfma<<<512, 512, 0, stream>>>(x, cond, eps, b1, b2, b3, ws, out);
}

// Round 9
// 4591.792 us; speedup vs baseline: 1.0179x; 1.0179x over previous
//
#include <hip/hip_runtime.h>

// FFJORD B=4096 D=64 C=16 H=512, NBIJ=2, NSTEPS=8 RK4 -> 64 sequential MLP+VJP evals.
// Round 9: R8 (2 blocks/CU, M=8, grid 512, launch_bounds(512,4), 66KB LDS) with all
// strip GEMMs reshaped to TWO sequential 2-col-tile halves so arch VGPRs fit the ~64
// ceiling at 4 waves/SIMD (R8's 4-tile bodies spilled: FETCH 2.4GB). Accs in AGPRs.

typedef __attribute__((ext_vector_type(8))) short short8;
typedef __attribute__((ext_vector_type(4))) float f32x4;

#define MFMA_B16(a, b, c) __builtin_amdgcn_mfma_f32_16x16x32_bf16((a), (b), (c), 0, 0, 0)

__device__ __forceinline__ unsigned short f2bf(float f) {
  union { float f; unsigned u; } v; v.f = f;
  return (unsigned short)((v.u + 0x7FFFu + ((v.u >> 16) & 1u)) >> 16);
}
__device__ __forceinline__ float bf2f(unsigned short u) {
  union { unsigned u; float f; } v; v.u = ((unsigned)u) << 16; return v.f;
}
__device__ __forceinline__ float fast_tanh(float x) {
  float e = __expf(2.f * x);
  return 1.f - 2.f * __builtin_amdgcn_rcpf(e + 1.f);
}

// ws layout (ushort units), all bf16 column-major W[n][k]:
// W1f [2][512][96]  @ 0        (k>=81 zero-padded)
// W2f [2][512][512] @ 98304    (W2^T data: forward B)
// W2b [2][512][512] @ 622592   (plain W2: backward B)
// W3f [2][64][512]  @ 1146880  (W3^T: forward B)
// W3b [2][512][64]  @ 1212416  (plain W3: B for e3 = eps@W3^T, once per bijector)
// W1y [2][64][512]  @ 1277952  (first 64 rows of W1)

__global__ void prep_bf16(const float* __restrict__ W1, const float* __restrict__ W2,
                          const float* __restrict__ W3, unsigned short* __restrict__ ws) {
  int o = blockIdx.x * 256 + threadIdx.x;
  if (o < 98304) {
    int ib = o / 49152, r = o % 49152, n = r / 96, k = r % 96;
    ws[o] = (k < 81) ? f2bf(W1[(size_t)ib * 41472 + k * 512 + n]) : (unsigned short)0;
  } else if (o < 622592) {
    int o2 = o - 98304;
    int ib = o2 / 262144, r = o2 % 262144, n = r / 512, k = r % 512;
    ws[o] = f2bf(W2[(size_t)ib * 262144 + k * 512 + n]);
  } else if (o < 1146880) {
    ws[o] = f2bf(W2[o - 622592]);
  } else if (o < 1212416) {
    int o2 = o - 1146880;
    int ib = o2 / 32768, r = o2 % 32768, n = r / 512, k = r % 512;
    ws[o] = f2bf(W3[(size_t)ib * 32768 + k * 64 + n]);
  } else if (o < 1277952) {
    ws[o] = f2bf(W3[o - 1212416]);
  } else if (o < 1343488) {
    int o2 = o - 1277952;
    int ib = o2 / 32768, r = o2 % 32768, n = r / 512, k = r % 512;
    ws[o] = f2bf(W1[(size_t)ib * 41472 + n * 512 + k]);
  }
}

#define ZS 104   // z A-buffer stride (K=96 used)
#define HS 520   // h buffers stride (K=512)
#define ES 72    // eps stride (K=64)

__global__ __launch_bounds__(512, 4) void ffjord_mfma(
    const float* __restrict__ x, const float* __restrict__ cond, const float* __restrict__ eps,
    const float* __restrict__ b1g, const float* __restrict__ b2g, const float* __restrict__ b3g,
    const unsigned short* __restrict__ ws, float* __restrict__ out) {
  __shared__ unsigned short zA[16 * ZS];
  __shared__ unsigned short h1A[16 * HS];   // h1; overwritten by g1 in GEMM4b
  __shared__ unsigned short h2A[16 * HS];   // h2; overwritten by g2 (in-place) after GEMM3f
  __shared__ unsigned short e3A[16 * HS];   // e3 = eps @ W3^T, constant per bijector
  __shared__ unsigned short epsA[16 * ES];
  __shared__ float eps_s[8][64];
  __shared__ float f_s[8][64];
  __shared__ float ycur[8][64], ytmp[8][64], yacc[8][64];
  __shared__ float l_row[8], ld_row[8], ldacc[8];

  const int t = threadIdx.x;
  const int wave = t >> 6;
  const int lane = t & 63;
  const int lane15 = lane & 15;
  const int q8 = (lane >> 4) * 8;       // frag k-offset; C/D row base = q8>>1
  const int row0 = blockIdx.x * 8;
  const int ws64 = wave * 64;
  const int tm = t >> 6, td = t & 63;   // thread-own element (512 = 8x64)

  // init: rows 0..7 state; zero MFMA A-rows 8..15 of zA/epsA
  {
    float xv = x[(size_t)(row0 + tm) * 64 + td];
    ycur[tm][td] = xv; ytmp[tm][td] = xv;
  }
  for (int e = t; e < 8 * ZS; e += 512) zA[8 * ZS + e] = 0;
  for (int e = t; e < 8 * ES; e += 512) epsA[8 * ES + e] = 0;
  if (t < 256) {
    int m = t >> 5, kk = t & 31;   // rows 0..7, cols 64..95
    zA[m * ZS + 64 + kk] = (kk < 16) ? f2bf(cond[(size_t)(row0 + m) * 16 + kk]) : (unsigned short)0;
  }
  if (t < 8) ld_row[t] = 0.f;

  const float dt = 0.125f;
  const float w06 = dt / 6.f, w13 = dt / 3.f;

  for (int ib = 0; ib < 2; ++ib) {
    const unsigned short* W1f = ws + 0       + ib * 49152;
    const unsigned short* W2f = ws + 98304   + ib * 262144;
    const unsigned short* W2b = ws + 622592  + ib * 262144;
    const unsigned short* W3f = ws + 1146880 + ib * 32768;
    const unsigned short* W3b = ws + 1212416 + ib * 32768;
    const unsigned short* W1y = ws + 1277952 + ib * 32768;
    const float* b1b = b1g + ib * 512;
    const float* b2b = b2g + ib * 512;
    const float* b3b = b3g + ib * 64;

    {
      float ev = eps[((size_t)ib * 4096 + row0 + tm) * 64 + td];
      eps_s[tm][td] = ev;
      epsA[tm * ES + td] = f2bf(ev);
    }
    __syncthreads();

    // ---- e3 = eps @ W3^T (N=512, K=64), ONCE per bijector; 2-col-tile halves ----
    #pragma unroll 1
    for (int h = 0; h < 2; ++h) {
      f32x4 a0 = {0,0,0,0}, a1 = {0,0,0,0};
      const unsigned short* ap = epsA + lane15 * ES + q8;
      const unsigned short* wp = W3b + (size_t)(ws64 + 32 * h + lane15) * 64 + q8;
      #pragma unroll
      for (int kk = 0; kk < 64; kk += 32) {
        short8 a = *(const short8*)(ap + kk);
        a0 = MFMA_B16(a, *(const short8*)(wp + kk),           a0);
        a1 = MFMA_B16(a, *(const short8*)(wp + 16 * 64 + kk), a1);
      }
      f32x4 acc[2] = {a0, a1};
      #pragma unroll
      for (int j = 0; j < 2; ++j) {
        int n = ws64 + (2 * h + j) * 16 + lane15;
        #pragma unroll
        for (int rg = 0; rg < 4; ++rg)
          e3A[((q8 >> 1) + rg) * HS + n] = f2bf(acc[j][rg]);
      }
    }
    __syncthreads();

    for (int it = 0; it < 32; ++it) {
      const int s = it & 3;
      const float te = (it >> 2) * dt + ((s == 0) ? 0.f : (s == 3) ? dt : 0.5f * dt);

      // ---- z build + zero accumulators ----
      zA[tm * ZS + td] = f2bf(ytmp[tm][td]);
      f_s[tm][td] = 0.f;
      if (t < 8) { zA[t * ZS + 80] = f2bf(te); l_row[t] = 0.f; }
      __syncthreads();

      // ---- GEMM1: h1 = tanh(z @ W1 + b1), K=96, N=512; halves ----
      #pragma unroll 1
      for (int h = 0; h < 2; ++h) {
        f32x4 a0 = {0,0,0,0}, a1 = {0,0,0,0};
        const unsigned short* ap = zA + lane15 * ZS + q8;
        const unsigned short* wp = W1f + (size_t)(ws64 + 32 * h + lane15) * 96 + q8;
        #pragma unroll
        for (int k0 = 0; k0 < 96; k0 += 32) {
          short8 a = *(const short8*)(ap + k0);
          a0 = MFMA_B16(a, *(const short8*)(wp + k0),           a0);
          a1 = MFMA_B16(a, *(const short8*)(wp + 16 * 96 + k0), a1);
        }
        f32x4 acc[2] = {a0, a1};
        #pragma unroll
        for (int j = 0; j < 2; ++j) {
          int n = ws64 + (2 * h + j) * 16 + lane15;
          float bias = b1b[n];
          #pragma unroll
          for (int rg = 0; rg < 4; ++rg)
            h1A[((q8 >> 1) + rg) * HS + n] = f2bf(fast_tanh(acc[j][rg] + bias));
        }
      }
      __syncthreads();

      // ---- GEMM2: h2 = tanh(h1 @ W2 + b2), K=512, N=512; halves ----
      #pragma unroll 1
      for (int h = 0; h < 2; ++h) {
        f32x4 a0 = {0,0,0,0}, a1 = {0,0,0,0};
        const unsigned short* ap = h1A + lane15 * HS + q8;
        const unsigned short* wp = W2f + (size_t)(ws64 + 32 * h + lane15) * 512 + q8;
        #pragma unroll 2
        for (int k0 = 0; k0 < 512; k0 += 32) {
          short8 a = *(const short8*)(ap + k0);
          a0 = MFMA_B16(a, *(const short8*)(wp + k0),            a0);
          a1 = MFMA_B16(a, *(const short8*)(wp + 16 * 512 + k0), a1);
        }
        f32x4 acc[2] = {a0, a1};
        #pragma unroll
        for (int j = 0; j < 2; ++j) {
          int n = ws64 + (2 * h + j) * 16 + lane15;
          float bias = b2b[n];
          #pragma unroll
          for (int rg = 0; rg < 4; ++rg)
            h2A[((q8 >> 1) + rg) * HS + n] = f2bf(fast_tanh(acc[j][rg] + bias));
        }
      }
      __syncthreads();

      // ---- GEMM3f: f += h2 @ W3f (N=64, K split 8 ways x 64); halves ----
      #pragma unroll 1
      for (int h = 0; h < 2; ++h) {
        f32x4 a0 = {0,0,0,0}, a1 = {0,0,0,0};
        const unsigned short* ap = h2A + lane15 * HS + ws64 + q8;
        const unsigned short* wp = W3f + (size_t)lane15 * 512 + ws64 + q8 + (size_t)(2 * h) * 8192;
        #pragma unroll
        for (int kk = 0; kk < 64; kk += 32) {
          short8 a = *(const short8*)(ap + kk);
          a0 = MFMA_B16(a, *(const short8*)(wp + kk),        a0);
          a1 = MFMA_B16(a, *(const short8*)(wp + 8192 + kk), a1);
        }
        if (lane < 32) {   // C rows 0..7 only
          f32x4 acc[2] = {a0, a1};
          #pragma unroll
          for (int j = 0; j < 2; ++j)
            #pragma unroll
            for (int rg = 0; rg < 4; ++rg)
              atomicAdd(&f_s[(q8 >> 1) + rg][(2 * h + j) * 16 + lane15], acc[j][rg]);
        }
      }
      __syncthreads();

      // ---- g2 = e3 * (1 - h2^2) IN-PLACE into h2A (rows 8..15 stay 0: e3 rows 8..15 = 0) ----
      #pragma unroll
      for (int j = 0; j < 16; ++j) {
        int idx = t + j * 512;
        int m = idx >> 9, n = idx & 511;
        float hh = bf2f(h2A[m * HS + n]);
        h2A[m * HS + n] = f2bf(bf2f(e3A[m * HS + n]) * (1.f - hh * hh));
      }
      __syncthreads();

      // ---- GEMM4b: g1 = (g2 @ W2^T) * (1 - h1^2) -> h1A in place; halves ----
      #pragma unroll 1
      for (int h = 0; h < 2; ++h) {
        f32x4 a0 = {0,0,0,0}, a1 = {0,0,0,0};
        const unsigned short* ap = h2A + lane15 * HS + q8;
        const unsigned short* wp = W2b + (size_t)(ws64 + 32 * h + lane15) * 512 + q8;
        #pragma unroll 2
        for (int k0 = 0; k0 < 512; k0 += 32) {
          short8 a = *(const short8*)(ap + k0);
          a0 = MFMA_B16(a, *(const short8*)(wp + k0),            a0);
          a1 = MFMA_B16(a, *(const short8*)(wp + 16 * 512 + k0), a1);
        }
        f32x4 acc[2] = {a0, a1};
        #pragma unroll
        for (int j = 0; j < 2; ++j) {
          int n = ws64 + (2 * h + j) * 16 + lane15;
          #pragma unroll
          for (int rg = 0; rg < 4; ++rg) {
            int m = (q8 >> 1) + rg;
            float hh = bf2f(h1A[m * HS + n]);
            h1A[m * HS + n] = f2bf(acc[j][rg] * (1.f - hh * hh));
          }
        }
      }
      __syncthreads();

      // ---- GEMM5b: gz = g1 @ W1y^T (N=64, K split 8 ways); halves; l = sum(gz*eps) ----
      {
        float p0 = 0.f, p1 = 0.f, p2 = 0.f, p3 = 0.f;
        #pragma unroll 1
        for (int h = 0; h < 2; ++h) {
          f32x4 a0 = {0,0,0,0}, a1 = {0,0,0,0};
          const unsigned short* ap = h1A + lane15 * HS + ws64 + q8;
          const unsigned short* wp = W1y + (size_t)lane15 * 512 + ws64 + q8 + (size_t)(2 * h) * 8192;
          #pragma unroll
          for (int kk = 0; kk < 64; kk += 32) {
            short8 a = *(const short8*)(ap + kk);
            a0 = MFMA_B16(a, *(const short8*)(wp + kk),        a0);
            a1 = MFMA_B16(a, *(const short8*)(wp + 8192 + kk), a1);
          }
          int c0 = 32 * h + lane15, c1 = 32 * h + 16 + lane15;
          int mb = q8 >> 1;
          p0 += a0[0] * eps_s[mb + 0][c0] + a1[0] * eps_s[mb + 0][c1];
          p1 += a0[1] * eps_s[mb + 1][c0] + a1[1] * eps_s[mb + 1][c1];
          p2 += a0[2] * eps_s[mb + 2][c0] + a1[2] * eps_s[mb + 2][c1];
          p3 += a0[3] * eps_s[mb + 3][c0] + a1[3] * eps_s[mb + 3][c1];
        }
        if (lane < 32) {   // C rows 0..7 only
          float pr[4] = {p0, p1, p2, p3};
          #pragma unroll
          for (int rg = 0; rg < 4; ++rg) {
            float p = pr[rg];
            #pragma unroll
            for (int o = 1; o < 16; o <<= 1) p += __shfl_xor(p, o);
            if (lane15 == 0) atomicAdd(&l_row[(q8 >> 1) + rg], p);
          }
        }
      }
      __syncthreads();

      // ---- RK4 update (thread owns (tm,td)) ----
      {
        const float wk = (s == 0 || s == 3) ? w06 : w13;
        float fv = f_s[tm][td] + b3b[td];
        if (s == 0)      yacc[tm][td] = ycur[tm][td] + w06 * fv;
        else if (s < 3)  yacc[tm][td] += wk * fv;
        if (s < 3) {
          ytmp[tm][td] = ycur[tm][td] + ((s == 2) ? dt : 0.5f * dt) * fv;
        } else {
          float yn = yacc[tm][td] + w06 * fv;
          ycur[tm][td] = yn; ytmp[tm][td] = yn;
        }
        if (t < 8) {
          float lv = l_row[t];
          if (s == 0)      ldacc[t] = w06 * lv;
          else if (s < 3)  ldacc[t] += wk * lv;
          else             ld_row[t] += ldacc[t] + w06 * lv;
        }
      }
      __syncthreads();
    }
  }

  out[(size_t)(row0 + tm) * 65 + td] = ycur[tm][td];
  if (t < 8) out[(size_t)(row0 + t) * 65 + 64] = ld_row[t];
}

extern "C" void kernel_launch(void* const* d_in, const int* in_sizes, int n_in,
                              void* d_out, int out_size, void* d_ws, size_t ws_size,
                              hipStream_t stream) {
  (void)in_sizes; (void)n_in; (void)out_size; (void)ws_size;
  const float* x    = (const float*)d_in[0];
  const float* cond = (const float*)d_in[1];
  const float* eps  = (const float*)d_in[2];
  const float* W1   = (const float*)d_in[3];
  const float* b1   = (const float*)d_in[4];
  const float* W2   = (const float*)d_in[5];
  const float* b2   = (const float*)d_in[6];
  const float* W3   = (const float*)d_in[7];
  const float* b3   = (const float*)d_in[8];
  float* out = (float*)d_out;
  unsigned short* ws = (unsigned short*)d_ws;

  const int prep_total = 1343488;
  prep_bf16<<<(prep_total + 255) / 256, 256, 0, stream>>>(W1, W2, W3, ws);
  ffjord_mfma<<<512, 512, 0, stream>>>(x, cond, eps, b1, b2, b3, ws, out);
}

// Round 10
// 3491.324 us; speedup vs baseline: 1.3388x; 1.3152x over previous
//
#include <hip/hip_runtime.h>

// FFJORD B=4096 D=64 C=16 H=512, NBIJ=2, NSTEPS=8 RK4 -> 64 sequential MLP+VJP evals.
// Round 10: M=16 rows/block (grid 256 = minimal weight traffic), 1024 threads = 16
// waves/CU (4/SIMD), waves own 32-wide N-strips. Slim 2-col-tile GEMM bodies (R9-proven
// spill-free at the 4-waves/EU register target: 56 arch VGPR). e3 = eps@W3^T hoisted per
// bijector; g2 in-place into h2A. LDS ~75KB, 1 block/CU.

typedef __attribute__((ext_vector_type(8))) short short8;
typedef __attribute__((ext_vector_type(4))) float f32x4;

#define MFMA_B16(a, b, c) __builtin_amdgcn_mfma_f32_16x16x32_bf16((a), (b), (c), 0, 0, 0)

__device__ __forceinline__ unsigned short f2bf(float f) {
  union { float f; unsigned u; } v; v.f = f;
  return (unsigned short)((v.u + 0x7FFFu + ((v.u >> 16) & 1u)) >> 16);
}
__device__ __forceinline__ float bf2f(unsigned short u) {
  union { unsigned u; float f; } v; v.u = ((unsigned)u) << 16; return v.f;
}
__device__ __forceinline__ float fast_tanh(float x) {
  float e = __expf(2.f * x);
  return 1.f - 2.f * __builtin_amdgcn_rcpf(e + 1.f);
}

// ws layout (ushort units), all bf16 column-major W[n][k]:
// W1f [2][512][96]  @ 0        (k>=81 zero-padded)
// W2f [2][512][512] @ 98304    (W2^T data: forward B)
// W2b [2][512][512] @ 622592   (plain W2: backward B)
// W3f [2][64][512]  @ 1146880  (W3^T: forward B)
// W3b [2][512][64]  @ 1212416  (plain W3: B for e3 = eps@W3^T, once per bijector)
// W1y [2][64][512]  @ 1277952  (first 64 rows of W1)

__global__ void prep_bf16(const float* __restrict__ W1, const float* __restrict__ W2,
                          const float* __restrict__ W3, unsigned short* __restrict__ ws) {
  int o = blockIdx.x * 256 + threadIdx.x;
  if (o < 98304) {
    int ib = o / 49152, r = o % 49152, n = r / 96, k = r % 96;
    ws[o] = (k < 81) ? f2bf(W1[(size_t)ib * 41472 + k * 512 + n]) : (unsigned short)0;
  } else if (o < 622592) {
    int o2 = o - 98304;
    int ib = o2 / 262144, r = o2 % 262144, n = r / 512, k = r % 512;
    ws[o] = f2bf(W2[(size_t)ib * 262144 + k * 512 + n]);
  } else if (o < 1146880) {
    ws[o] = f2bf(W2[o - 622592]);
  } else if (o < 1212416) {
    int o2 = o - 1146880;
    int ib = o2 / 32768, r = o2 % 32768, n = r / 512, k = r % 512;
    ws[o] = f2bf(W3[(size_t)ib * 32768 + k * 64 + n]);
  } else if (o < 1277952) {
    ws[o] = f2bf(W3[o - 1212416]);
  } else if (o < 1343488) {
    int o2 = o - 1277952;
    int ib = o2 / 32768, r = o2 % 32768, n = r / 512, k = r % 512;
    ws[o] = f2bf(W1[(size_t)ib * 41472 + n * 512 + k]);
  }
}

#define ZS 104   // z A-buffer stride (K=96 used)
#define HS 520   // h buffers stride (K=512)
#define ES 72    // eps stride (K=64)

__global__ __launch_bounds__(1024, 4) void ffjord_mfma(
    const float* __restrict__ x, const float* __restrict__ cond, const float* __restrict__ eps,
    const float* __restrict__ b1g, const float* __restrict__ b2g, const float* __restrict__ b3g,
    const unsigned short* __restrict__ ws, float* __restrict__ out) {
  __shared__ unsigned short zA[16 * ZS];
  __shared__ unsigned short h1A[16 * HS];   // h1; overwritten by g1 in GEMM4b
  __shared__ unsigned short h2A[16 * HS];   // h2; overwritten by g2 (in-place) after GEMM3f
  __shared__ unsigned short e3A[16 * HS];   // e3 = eps @ W3^T, constant per bijector
  __shared__ unsigned short epsA[16 * ES];
  __shared__ float eps_s[16][64];
  __shared__ float f_s[16][64];
  __shared__ float ycur[16][64], ytmp[16][64], yacc[16][64];
  __shared__ float l_row[16], ld_row[16], ldacc[16];

  const int t = threadIdx.x;
  const int wave = t >> 6;               // 0..15
  const int lane = t & 63;
  const int lane15 = lane & 15;
  const int q8 = (lane >> 4) * 8;        // frag k-offset; C/D row base = q8>>1
  const int row0 = blockIdx.x * 16;
  const int ws32 = wave * 32;            // wave's 32-wide N-strip base
  const int tm = t >> 6, td = t & 63;    // thread-own element (1024 = 16x64)

  // init
  {
    float xv = x[(size_t)(row0 + tm) * 64 + td];
    ycur[tm][td] = xv; ytmp[tm][td] = xv;
  }
  if (t < 512) {
    int m = t >> 5, kk = t & 31;   // rows 0..15, cols 64..95
    zA[m * ZS + 64 + kk] = (kk < 16) ? f2bf(cond[(size_t)(row0 + m) * 16 + kk]) : (unsigned short)0;
  }
  if (t < 16) ld_row[t] = 0.f;

  const float dt = 0.125f;
  const float w06 = dt / 6.f, w13 = dt / 3.f;

  for (int ib = 0; ib < 2; ++ib) {
    const unsigned short* W1f = ws + 0       + ib * 49152;
    const unsigned short* W2f = ws + 98304   + ib * 262144;
    const unsigned short* W2b = ws + 622592  + ib * 262144;
    const unsigned short* W3f = ws + 1146880 + ib * 32768;
    const unsigned short* W3b = ws + 1212416 + ib * 32768;
    const unsigned short* W1y = ws + 1277952 + ib * 32768;
    const float* b1b = b1g + ib * 512;
    const float* b2b = b2g + ib * 512;
    const float* b3b = b3g + ib * 64;

    {
      float ev = eps[((size_t)ib * 4096 + row0 + tm) * 64 + td];
      eps_s[tm][td] = ev;
      epsA[tm * ES + td] = f2bf(ev);
    }
    __syncthreads();

    // ---- e3 = eps @ W3^T (N=512, K=64), ONCE per bijector; 32-wide strip/wave ----
    {
      f32x4 a0 = {0,0,0,0}, a1 = {0,0,0,0};
      const unsigned short* ap = epsA + lane15 * ES + q8;
      const unsigned short* wp = W3b + (size_t)(ws32 + lane15) * 64 + q8;
      #pragma unroll
      for (int kk = 0; kk < 64; kk += 32) {
        short8 a = *(const short8*)(ap + kk);
        a0 = MFMA_B16(a, *(const short8*)(wp + kk),           a0);
        a1 = MFMA_B16(a, *(const short8*)(wp + 16 * 64 + kk), a1);
      }
      f32x4 acc[2] = {a0, a1};
      #pragma unroll
      for (int j = 0; j < 2; ++j) {
        int n = ws32 + j * 16 + lane15;
        #pragma unroll
        for (int rg = 0; rg < 4; ++rg)
          e3A[((q8 >> 1) + rg) * HS + n] = f2bf(acc[j][rg]);
      }
    }
    __syncthreads();

    for (int it = 0; it < 32; ++it) {
      const int s = it & 3;
      const float te = (it >> 2) * dt + ((s == 0) ? 0.f : (s == 3) ? dt : 0.5f * dt);

      // ---- z build + zero accumulators ----
      zA[tm * ZS + td] = f2bf(ytmp[tm][td]);
      f_s[tm][td] = 0.f;
      if (t < 16) { zA[t * ZS + 80] = f2bf(te); l_row[t] = 0.f; }
      __syncthreads();

      // ---- GEMM1: h1 = tanh(z @ W1 + b1), K=96, N=512 ----
      {
        f32x4 a0 = {0,0,0,0}, a1 = {0,0,0,0};
        const unsigned short* ap = zA + lane15 * ZS + q8;
        const unsigned short* wp = W1f + (size_t)(ws32 + lane15) * 96 + q8;
        #pragma unroll
        for (int k0 = 0; k0 < 96; k0 += 32) {
          short8 a = *(const short8*)(ap + k0);
          a0 = MFMA_B16(a, *(const short8*)(wp + k0),           a0);
          a1 = MFMA_B16(a, *(const short8*)(wp + 16 * 96 + k0), a1);
        }
        f32x4 acc[2] = {a0, a1};
        #pragma unroll
        for (int j = 0; j < 2; ++j) {
          int n = ws32 + j * 16 + lane15;
          float bias = b1b[n];
          #pragma unroll
          for (int rg = 0; rg < 4; ++rg)
            h1A[((q8 >> 1) + rg) * HS + n] = f2bf(fast_tanh(acc[j][rg] + bias));
        }
      }
      __syncthreads();

      // ---- GEMM2: h2 = tanh(h1 @ W2 + b2), K=512, N=512 ----
      {
        f32x4 a0 = {0,0,0,0}, a1 = {0,0,0,0};
        const unsigned short* ap = h1A + lane15 * HS + q8;
        const unsigned short* wp = W2f + (size_t)(ws32 + lane15) * 512 + q8;
        #pragma unroll 2
        for (int k0 = 0; k0 < 512; k0 += 32) {
          short8 a = *(const short8*)(ap + k0);
          a0 = MFMA_B16(a, *(const short8*)(wp + k0),            a0);
          a1 = MFMA_B16(a, *(const short8*)(wp + 16 * 512 + k0), a1);
        }
        f32x4 acc[2] = {a0, a1};
        #pragma unroll
        for (int j = 0; j < 2; ++j) {
          int n = ws32 + j * 16 + lane15;
          float bias = b2b[n];
          #pragma unroll
          for (int rg = 0; rg < 4; ++rg)
            h2A[((q8 >> 1) + rg) * HS + n] = f2bf(fast_tanh(acc[j][rg] + bias));
        }
      }
      __syncthreads();

      // ---- GEMM3f: f += h2 @ W3f (N=64, K split 16 ways x 32); 2 halves x 2 tiles ----
      #pragma unroll 1
      for (int h = 0; h < 2; ++h) {
        f32x4 a0 = {0,0,0,0}, a1 = {0,0,0,0};
        const unsigned short* ap = h2A + lane15 * HS + ws32 + q8;
        const unsigned short* wp = W3f + (size_t)(2 * h * 16 + lane15) * 512 + ws32 + q8;
        {
          short8 a = *(const short8*)(ap);
          a0 = MFMA_B16(a, *(const short8*)(wp),        a0);
          a1 = MFMA_B16(a, *(const short8*)(wp + 8192), a1);   // +16 rows of n
        }
        f32x4 acc[2] = {a0, a1};
        #pragma unroll
        for (int j = 0; j < 2; ++j)
          #pragma unroll
          for (int rg = 0; rg < 4; ++rg)
            atomicAdd(&f_s[(q8 >> 1) + rg][(2 * h + j) * 16 + lane15], acc[j][rg]);
      }
      __syncthreads();

      // ---- g2 = e3 * (1 - h2^2) IN-PLACE into h2A ----
      #pragma unroll
      for (int j = 0; j < 8; ++j) {
        int idx = t + j * 1024;
        int m = idx >> 9, n = idx & 511;
        float hh = bf2f(h2A[m * HS + n]);
        h2A[m * HS + n] = f2bf(bf2f(e3A[m * HS + n]) * (1.f - hh * hh));
      }
      __syncthreads();

      // ---- GEMM4b: g1 = (g2 @ W2^T) * (1 - h1^2) -> h1A in place ----
      {
        f32x4 a0 = {0,0,0,0}, a1 = {0,0,0,0};
        const unsigned short* ap = h2A + lane15 * HS + q8;
        const unsigned short* wp = W2b + (size_t)(ws32 + lane15) * 512 + q8;
        #pragma unroll 2
        for (int k0 = 0; k0 < 512; k0 += 32) {
          short8 a = *(const short8*)(ap + k0);
          a0 = MFMA_B16(a, *(const short8*)(wp + k0),            a0);
          a1 = MFMA_B16(a, *(const short8*)(wp + 16 * 512 + k0), a1);
        }
        f32x4 acc[2] = {a0, a1};
        #pragma unroll
        for (int j = 0; j < 2; ++j) {
          int n = ws32 + j * 16 + lane15;
          #pragma unroll
          for (int rg = 0; rg < 4; ++rg) {
            int m = (q8 >> 1) + rg;
            float hh = bf2f(h1A[m * HS + n]);
            h1A[m * HS + n] = f2bf(acc[j][rg] * (1.f - hh * hh));
          }
        }
      }
      __syncthreads();

      // ---- GEMM5b: gz = g1 @ W1y^T (N=64, K split 16 ways); l = sum(gz*eps) ----
      {
        float p0 = 0.f, p1 = 0.f, p2 = 0.f, p3 = 0.f;
        #pragma unroll 1
        for (int h = 0; h < 2; ++h) {
          f32x4 a0 = {0,0,0,0}, a1 = {0,0,0,0};
          const unsigned short* ap = h1A + lane15 * HS + ws32 + q8;
          const unsigned short* wp = W1y + (size_t)(2 * h * 16 + lane15) * 512 + ws32 + q8;
          {
            short8 a = *(const short8*)(ap);
            a0 = MFMA_B16(a, *(const short8*)(wp),        a0);
            a1 = MFMA_B16(a, *(const short8*)(wp + 8192), a1);
          }
          int c0 = 2 * h * 16 + lane15, c1 = (2 * h + 1) * 16 + lane15;
          int mb = q8 >> 1;
          p0 += a0[0] * eps_s[mb + 0][c0] + a1[0] * eps_s[mb + 0][c1];
          p1 += a0[1] * eps_s[mb + 1][c0] + a1[1] * eps_s[mb + 1][c1];
          p2 += a0[2] * eps_s[mb + 2][c0] + a1[2] * eps_s[mb + 2][c1];
          p3 += a0[3] * eps_s[mb + 3][c0] + a1[3] * eps_s[mb + 3][c1];
        }
        float pr[4] = {p0, p1, p2, p3};
        #pragma unroll
        for (int rg = 0; rg < 4; ++rg) {
          float p = pr[rg];
          #pragma unroll
          for (int o = 1; o < 16; o <<= 1) p += __shfl_xor(p, o);
          if (lane15 == 0) atomicAdd(&l_row[(q8 >> 1) + rg], p);
        }
      }
      __syncthreads();

      // ---- RK4 update (thread owns (tm,td)) ----
      {
        const float wk = (s == 0 || s == 3) ? w06 : w13;
        float fv = f_s[tm][td] + b3b[td];
        if (s == 0)      yacc[tm][td] = ycur[tm][td] + w06 * fv;
        else if (s < 3)  yacc[tm][td] += wk * fv;
        if (s < 3) {
          ytmp[tm][td] = ycur[tm][td] + ((s == 2) ? dt : 0.5f * dt) * fv;
        } else {
          float yn = yacc[tm][td] + w06 * fv;
          ycur[tm][td] = yn; ytmp[tm][td] = yn;
        }
        if (t < 16) {
          float lv = l_row[t];
          if (s == 0)      ldacc[t] = w06 * lv;
          else if (s < 3)  ldacc[t] += wk * lv;
          else             ld_row[t] += ldacc[t] + w06 * lv;
        }
      }
      __syncthreads();
    }
  }

  out[(size_t)(row0 + tm) * 65 + td] = ycur[tm][td];
  if (t < 16) out[(size_t)(row0 + t) * 65 + 64] = ld_row[t];
}

extern "C" void kernel_launch(void* const* d_in, const int* in_sizes, int n_in,
                              void* d_out, int out_size, void* d_ws, size_t ws_size,
                              hipStream_t stream) {
  (void)in_sizes; (void)n_in; (void)out_size; (void)ws_size;
  const float* x    = (const float*)d_in[0];
  const float* cond = (const float*)d_in[1];
  const float* eps  = (const float*)d_in[2];
  const float* W1   = (const float*)d_in[3];
  const float* b1   = (const float*)d_in[4];
  const float* W2   = (const float*)d_in[5];
  const float* b2   = (const float*)d_in[6];
  const float* W3   = (const float*)d_in[7];
  const float* b3   = (const float*)d_in[8];
  float* out = (float*)d_out;
  unsigned short* ws = (unsigned short*)d_ws;

  const int prep_total = 1343488;
  prep_bf16<<<(prep_total + 255) / 256, 256, 0, stream>>>(W1, W2, W3, ws);
  ffjord_mfma<<<256, 1024, 0, stream>>>(x, cond, eps, b1, b2, b3, ws, out);
}

// Round 11
// 2804.867 us; speedup vs baseline: 1.6664x; 1.2447x over previous
//
#include <hip/hip_runtime.h>

// FFJORD B=4096 D=64 C=16 H=512, NBIJ=2, NSTEPS=8 RK4 -> 64 sequential MLP+VJP evals.
// Round 11: R6 (best, 2773us) + cross-block weight-stream decorrelation:
//  (a) wave N-strip rotated by (blockIdx>>3)&7 -> co-XCD blocks read different strips;
//  (b) K-loop phase rotation ((blockIdx>>3)&15)*32 with &511 wrap in the two K=512 GEMMs.
// Theory: ~12 B/cyc/CU plateau = same-line L2 bank serialization across ~32 lockstep
// blocks per XCD; decorrelation spreads instantaneous line working set.

typedef __attribute__((ext_vector_type(8))) short short8;
typedef __attribute__((ext_vector_type(4))) float f32x4;

#define MFMA_B16(a, b, c) __builtin_amdgcn_mfma_f32_16x16x32_bf16((a), (b), (c), 0, 0, 0)

__device__ __forceinline__ unsigned short f2bf(float f) {
  union { float f; unsigned u; } v; v.f = f;
  return (unsigned short)((v.u + 0x7FFFu + ((v.u >> 16) & 1u)) >> 16);
}
__device__ __forceinline__ float bf2f(unsigned short u) {
  union { unsigned u; float f; } v; v.u = ((unsigned)u) << 16; return v.f;
}
__device__ __forceinline__ float fast_tanh(float x) {
  float e = __expf(2.f * x);
  return 1.f - 2.f * __builtin_amdgcn_rcpf(e + 1.f);
}

// ws layout (ushort units), all bf16 column-major W[n][k]:
// W1f [2][512][96]  @ 0        (k>=81 zero-padded)
// W2f [2][512][512] @ 98304    (W2^T data: forward B)
// W2b [2][512][512] @ 622592   (plain W2: backward B)
// W3f [2][64][512]  @ 1146880  (W3^T: forward B)
// W3b [2][512][64]  @ 1212416  (plain W3: B for e3 = eps@W3^T, once per bijector)
// W1y [2][64][512]  @ 1277952  (first 64 rows of W1)

__global__ void prep_bf16(const float* __restrict__ W1, const float* __restrict__ W2,
                          const float* __restrict__ W3, unsigned short* __restrict__ ws) {
  int o = blockIdx.x * 256 + threadIdx.x;
  if (o < 98304) {
    int ib = o / 49152, r = o % 49152, n = r / 96, k = r % 96;
    ws[o] = (k < 81) ? f2bf(W1[(size_t)ib * 41472 + k * 512 + n]) : (unsigned short)0;
  } else if (o < 622592) {
    int o2 = o - 98304;
    int ib = o2 / 262144, r = o2 % 262144, n = r / 512, k = r % 512;
    ws[o] = f2bf(W2[(size_t)ib * 262144 + k * 512 + n]);
  } else if (o < 1146880) {
    ws[o] = f2bf(W2[o - 622592]);
  } else if (o < 1212416) {
    int o2 = o - 1146880;
    int ib = o2 / 32768, r = o2 % 32768, n = r / 512, k = r % 512;
    ws[o] = f2bf(W3[(size_t)ib * 32768 + k * 64 + n]);
  } else if (o < 1277952) {
    ws[o] = f2bf(W3[o - 1212416]);
  } else if (o < 1343488) {
    int o2 = o - 1277952;
    int ib = o2 / 32768, r = o2 % 32768, n = r / 512, k = r % 512;
    ws[o] = f2bf(W1[(size_t)ib * 41472 + n * 512 + k]);
  }
}

#define ZS 104   // z A-buffer stride (K=96 used)
#define HS 520   // h buffers stride (K=512)
#define ES 72    // eps stride (K=64)

__global__ __launch_bounds__(512) void ffjord_mfma(
    const float* __restrict__ x, const float* __restrict__ cond, const float* __restrict__ eps,
    const float* __restrict__ b1g, const float* __restrict__ b2g, const float* __restrict__ b3g,
    const unsigned short* __restrict__ ws, float* __restrict__ out) {
  __shared__ unsigned short zA[16 * ZS];
  __shared__ unsigned short h1A[16 * HS];   // h1; overwritten by g1 in GEMM4b
  __shared__ unsigned short h2A[16 * HS];
  __shared__ unsigned short g2A[16 * HS];
  __shared__ unsigned short e3A[16 * HS];   // e3 = eps @ W3^T, constant per bijector
  __shared__ unsigned short epsA[16 * ES];
  __shared__ float eps_s[16][64];
  __shared__ float f_s[16][64];
  __shared__ float ycur[16][64], ytmp[16][64], yacc[16][64];
  __shared__ float l_row[16], ld_row[16], ldacc[16];

  const int t = threadIdx.x;
  const int wave = t >> 6;
  const int lane = t & 63;
  const int lane15 = lane & 15;
  const int q8 = (lane >> 4) * 8;       // frag k-offset; C/D row base = q8>>1
  const int row0 = blockIdx.x * 16;
  const int rot = (blockIdx.x >> 3) & 7;          // co-XCD decorrelation
  const int ws64 = ((wave + rot) & 7) * 64;       // rotated N-strip / K-split index
  const unsigned kphase = ((blockIdx.x >> 3) & 15) * 32;  // K start phase (bytes-free, elem units)

  // init
  for (int e = t; e < 1024; e += 512) {
    int m = e >> 6, d = e & 63;
    float xv = x[(size_t)(row0 + m) * 64 + d];
    ycur[m][d] = xv; ytmp[m][d] = xv;
  }
  {
    int m = t >> 5, kk = t & 31;
    zA[m * ZS + 64 + kk] = (kk < 16) ? f2bf(cond[(size_t)(row0 + m) * 16 + kk]) : (unsigned short)0;
  }
  if (t < 16) ld_row[t] = 0.f;

  const float dt = 0.125f;
  const float w06 = dt / 6.f, w13 = dt / 3.f;

  for (int ib = 0; ib < 2; ++ib) {
    const unsigned short* W1f = ws + 0       + ib * 49152;
    const unsigned short* W2f = ws + 98304   + ib * 262144;
    const unsigned short* W2b = ws + 622592  + ib * 262144;
    const unsigned short* W3f = ws + 1146880 + ib * 32768;
    const unsigned short* W3b = ws + 1212416 + ib * 32768;
    const unsigned short* W1y = ws + 1277952 + ib * 32768;
    const float* b1b = b1g + ib * 512;
    const float* b2b = b2g + ib * 512;
    const float* b3b = b3g + ib * 64;

    for (int e = t; e < 1024; e += 512) {
      int m = e >> 6, d = e & 63;
      float ev = eps[((size_t)ib * 4096 + row0 + m) * 64 + d];
      eps_s[m][d] = ev;
      epsA[m * ES + d] = f2bf(ev);
    }
    __syncthreads();

    // ---- e3 = eps @ W3^T (N=512, K=64), ONCE per bijector ----
    {
      f32x4 a0 = {0,0,0,0}, a1 = {0,0,0,0}, a2 = {0,0,0,0}, a3 = {0,0,0,0};
      const unsigned short* ap = epsA + lane15 * ES + q8;
      const unsigned short* wp = W3b + (size_t)(ws64 + lane15) * 64 + q8;
      #pragma unroll
      for (int kk = 0; kk < 64; kk += 32) {
        short8 a = *(const short8*)(ap + kk);
        a0 = MFMA_B16(a, *(const short8*)(wp + kk),           a0);
        a1 = MFMA_B16(a, *(const short8*)(wp + 16 * 64 + kk), a1);
        a2 = MFMA_B16(a, *(const short8*)(wp + 32 * 64 + kk), a2);
        a3 = MFMA_B16(a, *(const short8*)(wp + 48 * 64 + kk), a3);
      }
      f32x4 acc[4] = {a0, a1, a2, a3};
      #pragma unroll
      for (int tl = 0; tl < 4; ++tl) {
        int n = ws64 + tl * 16 + lane15;
        #pragma unroll
        for (int rg = 0; rg < 4; ++rg)
          e3A[((q8 >> 1) + rg) * HS + n] = f2bf(acc[tl][rg]);
      }
    }
    __syncthreads();

    for (int it = 0; it < 32; ++it) {
      const int s = it & 3;
      const float te = (it >> 2) * dt + ((s == 0) ? 0.f : (s == 3) ? dt : 0.5f * dt);

      // ---- z build + zero accumulators ----
      for (int e = t; e < 1024; e += 512) {
        int m = e >> 6, d = e & 63;
        zA[m * ZS + d] = f2bf(ytmp[m][d]);
        f_s[m][d] = 0.f;
      }
      if (t < 16) { zA[t * ZS + 80] = f2bf(te); l_row[t] = 0.f; }
      __syncthreads();

      // ---- GEMM1: h1 = tanh(z @ W1 + b1), K=96, N=512 ----
      {
        f32x4 a0 = {0,0,0,0}, a1 = {0,0,0,0}, a2 = {0,0,0,0}, a3 = {0,0,0,0};
        const unsigned short* ap = zA + lane15 * ZS + q8;
        const unsigned short* wp = W1f + (size_t)(ws64 + lane15) * 96 + q8;
        #pragma unroll
        for (int k0 = 0; k0 < 96; k0 += 32) {
          short8 a = *(const short8*)(ap + k0);
          a0 = MFMA_B16(a, *(const short8*)(wp + k0),           a0);
          a1 = MFMA_B16(a, *(const short8*)(wp + 16 * 96 + k0), a1);
          a2 = MFMA_B16(a, *(const short8*)(wp + 32 * 96 + k0), a2);
          a3 = MFMA_B16(a, *(const short8*)(wp + 48 * 96 + k0), a3);
        }
        f32x4 acc[4] = {a0, a1, a2, a3};
        #pragma unroll
        for (int tl = 0; tl < 4; ++tl) {
          int n = ws64 + tl * 16 + lane15;
          float bias = b1b[n];
          #pragma unroll
          for (int rg = 0; rg < 4; ++rg)
            h1A[((q8 >> 1) + rg) * HS + n] = f2bf(fast_tanh(acc[tl][rg] + bias));
        }
      }
      __syncthreads();

      // ---- GEMM2: h2 = tanh(h1 @ W2 + b2), K=512, N=512, K-phase rotated ----
      {
        f32x4 a0 = {0,0,0,0}, a1 = {0,0,0,0}, a2 = {0,0,0,0}, a3 = {0,0,0,0};
        const unsigned short* ap = h1A + lane15 * HS + q8;
        const unsigned short* wp = W2f + (size_t)(ws64 + lane15) * 512 + q8;
        unsigned kk = kphase;
        #pragma unroll 8
        for (int i = 0; i < 16; ++i) {
          short8 a = *(const short8*)(ap + kk);
          a0 = MFMA_B16(a, *(const short8*)(wp + kk),            a0);
          a1 = MFMA_B16(a, *(const short8*)(wp + 16 * 512 + kk), a1);
          a2 = MFMA_B16(a, *(const short8*)(wp + 32 * 512 + kk), a2);
          a3 = MFMA_B16(a, *(const short8*)(wp + 48 * 512 + kk), a3);
          kk = (kk + 32) & 511;
        }
        f32x4 acc[4] = {a0, a1, a2, a3};
        #pragma unroll
        for (int tl = 0; tl < 4; ++tl) {
          int n = ws64 + tl * 16 + lane15;
          float bias = b2b[n];
          #pragma unroll
          for (int rg = 0; rg < 4; ++rg)
            h2A[((q8 >> 1) + rg) * HS + n] = f2bf(fast_tanh(acc[tl][rg] + bias));
        }
      }
      __syncthreads();

      // ---- g2 = e3 * (1 - h2^2), elementwise; GEMM3f: f += h2 @ W3f (K split 8 ways) ----
      {
        #pragma unroll
        for (int j = 0; j < 16; ++j) {
          int idx = t + j * 512;
          int m = idx >> 9, n = idx & 511;
          float h = bf2f(h2A[m * HS + n]);
          g2A[m * HS + n] = f2bf(bf2f(e3A[m * HS + n]) * (1.f - h * h));
        }
      }
      {
        f32x4 a0 = {0,0,0,0}, a1 = {0,0,0,0}, a2 = {0,0,0,0}, a3 = {0,0,0,0};
        const unsigned short* ap = h2A + lane15 * HS + ws64 + q8;
        const unsigned short* wp = W3f + (size_t)lane15 * 512 + ws64 + q8;
        #pragma unroll
        for (int kk = 0; kk < 64; kk += 32) {
          short8 a = *(const short8*)(ap + kk);
          a0 = MFMA_B16(a, *(const short8*)(wp + kk),            a0);
          a1 = MFMA_B16(a, *(const short8*)(wp + 16 * 512 + kk), a1);
          a2 = MFMA_B16(a, *(const short8*)(wp + 32 * 512 + kk), a2);
          a3 = MFMA_B16(a, *(const short8*)(wp + 48 * 512 + kk), a3);
        }
        f32x4 acc[4] = {a0, a1, a2, a3};
        #pragma unroll
        for (int tl = 0; tl < 4; ++tl)
          #pragma unroll
          for (int rg = 0; rg < 4; ++rg)
            atomicAdd(&f_s[(q8 >> 1) + rg][tl * 16 + lane15], acc[tl][rg]);
      }
      __syncthreads();

      // ---- GEMM4b: g1 = (g2 @ W2^T) * (1 - h1^2) -> h1A in place, K-phase rotated ----
      {
        f32x4 a0 = {0,0,0,0}, a1 = {0,0,0,0}, a2 = {0,0,0,0}, a3 = {0,0,0,0};
        const unsigned short* ap = g2A + lane15 * HS + q8;
        const unsigned short* wp = W2b + (size_t)(ws64 + lane15) * 512 + q8;
        unsigned kk = kphase;
        #pragma unroll 8
        for (int i = 0; i < 16; ++i) {
          short8 a = *(const short8*)(ap + kk);
          a0 = MFMA_B16(a, *(const short8*)(wp + kk),            a0);
          a1 = MFMA_B16(a, *(const short8*)(wp + 16 * 512 + kk), a1);
          a2 = MFMA_B16(a, *(const short8*)(wp + 32 * 512 + kk), a2);
          a3 = MFMA_B16(a, *(const short8*)(wp + 48 * 512 + kk), a3);
          kk = (kk + 32) & 511;
        }
        f32x4 acc[4] = {a0, a1, a2, a3};
        #pragma unroll
        for (int tl = 0; tl < 4; ++tl) {
          int n = ws64 + tl * 16 + lane15;
          #pragma unroll
          for (int rg = 0; rg < 4; ++rg) {
            int m = (q8 >> 1) + rg;
            float h = bf2f(h1A[m * HS + n]);
            h1A[m * HS + n] = f2bf(acc[tl][rg] * (1.f - h * h));
          }
        }
      }
      __syncthreads();

      // ---- GEMM5b: gz = g1 @ W1y^T (N=64, K split 8 ways), l = sum(gz*eps) ----
      {
        f32x4 a0 = {0,0,0,0}, a1 = {0,0,0,0}, a2 = {0,0,0,0}, a3 = {0,0,0,0};
        const unsigned short* ap = h1A + lane15 * HS + ws64 + q8;
        const unsigned short* wp = W1y + (size_t)lane15 * 512 + ws64 + q8;
        #pragma unroll
        for (int kk = 0; kk < 64; kk += 32) {
          short8 a = *(const short8*)(ap + kk);
          a0 = MFMA_B16(a, *(const short8*)(wp + kk),            a0);
          a1 = MFMA_B16(a, *(const short8*)(wp + 16 * 512 + kk), a1);
          a2 = MFMA_B16(a, *(const short8*)(wp + 32 * 512 + kk), a2);
          a3 = MFMA_B16(a, *(const short8*)(wp + 48 * 512 + kk), a3);
        }
        f32x4 acc[4] = {a0, a1, a2, a3};
        #pragma unroll
        for (int rg = 0; rg < 4; ++rg) {
          int m = (q8 >> 1) + rg;
          float p = acc[0][rg] * eps_s[m][lane15]
                  + acc[1][rg] * eps_s[m][16 + lane15]
                  + acc[2][rg] * eps_s[m][32 + lane15]
                  + acc[3][rg] * eps_s[m][48 + lane15];
          #pragma unroll
          for (int o = 1; o < 16; o <<= 1) p += __shfl_xor(p, o);
          if (lane15 == 0) atomicAdd(&l_row[m], p);
        }
      }
      __syncthreads();

      // ---- RK4 update ----
      {
        const float wk = (s == 0 || s == 3) ? w06 : w13;
        for (int e = t; e < 1024; e += 512) {
          int m = e >> 6, d = e & 63;
          float fv = f_s[m][d] + b3b[d];
          if (s == 0)      yacc[m][d] = ycur[m][d] + w06 * fv;
          else if (s < 3)  yacc[m][d] += wk * fv;
          if (s < 3) {
            ytmp[m][d] = ycur[m][d] + ((s == 2) ? dt : 0.5f * dt) * fv;
          } else {
            float yn = yacc[m][d] + w06 * fv;
            ycur[m][d] = yn; ytmp[m][d] = yn;
          }
        }
        if (t < 16) {
          float lv = l_row[t];
          if (s == 0)      ldacc[t] = w06 * lv;
          else if (s < 3)  ldacc[t] += wk * lv;
          else             ld_row[t] += ldacc[t] + w06 * lv;
        }
      }
      __syncthreads();
    }
  }

  for (int e = t; e < 1024; e += 512) {
    int m = e >> 6, d = e & 63;
    out[(size_t)(row0 + m) * 65 + d] = ycur[m][d];
  }
  if (t < 16) out[(size_t)(row0 + t) * 65 + 64] = ld_row[t];
}

extern "C" void kernel_launch(void* const* d_in, const int* in_sizes, int n_in,
                              void* d_out, int out_size, void* d_ws, size_t ws_size,
                              hipStream_t stream) {
  (void)in_sizes; (void)n_in; (void)out_size; (void)ws_size;
  const float* x    = (const float*)d_in[0];
  const float* cond = (const float*)d_in[1];
  const float* eps  = (const float*)d_in[2];
  const float* W1   = (const float*)d_in[3];
  const float* b1   = (const float*)d_in[4];
  const float* W2   = (const float*)d_in[5];
  const float* b2   = (const float*)d_in[6];
  const float* W3   = (const float*)d_in[7];
  const float* b3   = (const float*)d_in[8];
  float* out = (float*)d_out;
  unsigned short* ws = (unsigned short*)d_ws;

  const int prep_total = 1343488;
  prep_bf16<<<(prep_total + 255) / 256, 256, 0, stream>>>(W1, W2, W3, ws);
  ffjord_mfma<<<256, 512, 0, stream>>>(x, cond, eps, b1, b2, b3, ws, out);
}